// Round 7
// baseline (514.004 us; speedup 1.0000x reference)
//
#include <hip/hip_runtime.h>

#define T_TOK 8192
#define D_IN  1024
#define H_DIM 2048
#define DOUT_ 1024
#define NEXP  8
#define NPAIR 16384
#define BM 128
#define BN 128
#define BK 32
#define MAX_TILES 136

// gemm2 8-phase-style geometry
#define BM2 256
#define BN2T 256
#define BK2 64
#define NT2 (H_DIM / BK2)     // 32
#define MAX_TILES2 72

using bf16x8 = __attribute__((ext_vector_type(8))) __bf16;
using f32x4  = __attribute__((ext_vector_type(4))) float;

__device__ __forceinline__ unsigned short f2bf(float f) {
  unsigned int u = __float_as_uint(f);
  u += 0x7FFFu + ((u >> 16) & 1u);   // RNE
  return (unsigned short)(u >> 16);
}

__device__ __forceinline__ float bf2f(unsigned short b) {
  return __uint_as_float((unsigned int)b << 16);
}

__device__ __forceinline__ void gload16(const void* g, void* l) {
  __builtin_amdgcn_global_load_lds(
      (const __attribute__((address_space(1))) void*)g,
      (__attribute__((address_space(3))) void*)l, 16, 0, 0);
}

// Derive this block's (expert, tileStart, segBase, segN) from cnt[8] in
// registers (no meta-table cross-kernel communication).
struct TileInfo { int e, ts, segBase, segN; };
__device__ __forceinline__ bool tile_lookup(const int* __restrict__ cnt, int by, TileInfo& ti) {
  int tp = 0, acc = 0;
  ti.e = -1;
#pragma unroll
  for (int e = 0; e < NEXP; ++e) {
    int c = cnt[e];
    int nt = (c + BM - 1) / BM;
    if (ti.e < 0 && by < tp + nt) { ti.e = e; ti.ts = (by - tp) * BM; ti.segBase = acc; ti.segN = c; }
    tp += nt; acc += c;
  }
  return ti.e >= 0;
}

__device__ __forceinline__ bool tile_lookup2(const int* __restrict__ cnt, int by, TileInfo& ti) {
  int tp = 0, acc = 0;
  ti.e = -1;
#pragma unroll
  for (int e = 0; e < NEXP; ++e) {
    int c = cnt[e];
    int nt = (c + BM2 - 1) / BM2;
    if (ti.e < 0 && by < tp + nt) { ti.e = e; ti.ts = (by - tp) * BM2; ti.segBase = acc; ti.segN = c; }
    tp += nt; acc += c;
  }
  return ti.e >= 0;
}

// ---------------- conversion fp32 -> bf16 ----------------
__global__ void convert_kernel(const float* __restrict__ x, const float* __restrict__ wg,
                               const float* __restrict__ wu, const float* __restrict__ wd,
                               unsigned short* __restrict__ xb, unsigned short* __restrict__ wgb,
                               unsigned short* __restrict__ wub, unsigned short* __restrict__ wdb) {
  const long long nx = (long long)T_TOK * D_IN;
  const long long nw = (long long)NEXP * H_DIM * D_IN;
  const long long nd = (long long)NEXP * DOUT_ * H_DIM;
  const long long tot4 = (nx + 2 * nw + nd) >> 2;
  for (long long i = (long long)blockIdx.x * blockDim.x + threadIdx.x; i < tot4;
       i += (long long)gridDim.x * blockDim.x) {
    long long e = i << 2;
    const float* s; unsigned short* d; long long o;
    if (e < nx)              { s = x;  d = xb;  o = e; }
    else if (e < nx + nw)    { s = wg; d = wgb; o = e - nx; }
    else if (e < nx + 2*nw)  { s = wu; d = wub; o = e - nx - nw; }
    else                     { s = wd; d = wdb; o = e - nx - 2*nw; }
    float4 v = *(const float4*)(s + o);
    ushort4 b;
    b.x = f2bf(v.x); b.y = f2bf(v.y); b.z = f2bf(v.z); b.w = f2bf(v.w);
    *(ushort4*)(d + o) = b;
  }
}

// ---------------- dispatch build ----------------
__global__ void count_kernel(const int* __restrict__ idx, int* __restrict__ cnt) {
  int i = blockIdx.x * blockDim.x + threadIdx.x;
  if (i < NPAIR) atomicAdd(&cnt[idx[i]], 1);
}

__global__ void fill_kernel(const int* __restrict__ idx, const float* __restrict__ w,
                            const int* __restrict__ cnt, int* __restrict__ fill,
                            int* __restrict__ rows, float* __restrict__ wts,
                            int* __restrict__ inv) {
  int i = blockIdx.x * blockDim.x + threadIdx.x;
  if (i < NPAIR) {
    int e = idx[i];
    int base = 0, acc = 0;
#pragma unroll
    for (int k = 0; k < NEXP; ++k) {
      if (k == e) base = acc;
      acc += cnt[k];
    }
    int p = atomicAdd(&fill[e], 1);
    int pos = base + p;
    rows[pos] = i >> 1;       // token id (K=2)
    wts[pos] = w[i];
    inv[i] = pos;
  }
}

// ---------------- GEMM1: h = silu(x@Wg^T) * (x@Wu^T) ----------------
// (256,2) / VGPR 100 is the proven point (207 us). FROZEN.
__launch_bounds__(256, 2)
__global__ void gemm1_kernel(const unsigned short* __restrict__ xb,
                             const unsigned short* __restrict__ wgb,
                             const unsigned short* __restrict__ wub,
                             const int* __restrict__ cnt, const int* __restrict__ rows,
                             unsigned short* __restrict__ hbuf) {
  TileInfo ti;
  if (!tile_lookup(cnt, blockIdx.y, ti)) return;
  const int tid = threadIdx.x;
  const int e = ti.e, ts = ti.ts, segBase = ti.segBase, segN = ti.segN;
  const int ncol0 = blockIdx.x * BN;

  __shared__ unsigned short lds[2][3][BM][BK];   // A, Bg, Bu double-buffered: 48 KiB
  __shared__ int rows_s[BM];

  if (tid < BM) {
    int r = ts + tid;
    rows_s[tid] = rows[segBase + (r < segN ? r : 0)];
  }
  __syncthreads();

  const int r0 = tid >> 2, r1 = 64 + (tid >> 2);
  const int kq = (tid & 3) * 8;   // bf16 elements
  const int tok0 = rows_s[r0], tok1 = rows_s[r1];
  const unsigned short* ag0 = xb + (size_t)tok0 * D_IN + kq;
  const unsigned short* ag1 = xb + (size_t)tok1 * D_IN + kq;
  const unsigned short* wge = wgb + (size_t)e * H_DIM * D_IN;
  const unsigned short* wue = wub + (size_t)e * H_DIM * D_IN;
  const unsigned short* bg0 = wge + (size_t)(ncol0 + r0) * D_IN + kq;
  const unsigned short* bg1 = wge + (size_t)(ncol0 + r1) * D_IN + kq;
  const unsigned short* bu0 = wue + (size_t)(ncol0 + r0) * D_IN + kq;
  const unsigned short* bu1 = wue + (size_t)(ncol0 + r1) * D_IN + kq;

#define STAGE1(b, k0) do { \
    gload16(ag0 + (k0), &lds[b][0][r0][kq]); \
    gload16(ag1 + (k0), &lds[b][0][r1][kq]); \
    gload16(bg0 + (k0), &lds[b][1][r0][kq]); \
    gload16(bg1 + (k0), &lds[b][1][r1][kq]); \
    gload16(bu0 + (k0), &lds[b][2][r0][kq]); \
    gload16(bu1 + (k0), &lds[b][2][r1][kq]); \
  } while (0)

  f32x4 gacc[4][4] = {};
  f32x4 uacc[4][4] = {};
  const int lane = tid & 63, wid = tid >> 6;
  const int wm = (wid >> 1) * 64, wn = (wid & 1) * 64;
  const int fr = lane & 15, fq = lane >> 4;

  STAGE1(0, 0);
  __syncthreads();
  for (int kt = 0; kt < D_IN / BK; ++kt) {
    const int cur = kt & 1;
    if (kt + 1 < D_IN / BK) STAGE1(cur ^ 1, (kt + 1) * BK);
    bf16x8 af[4], bgf[4], buf_[4];
#pragma unroll
    for (int mf = 0; mf < 4; ++mf) af[mf]   = *(const bf16x8*)&lds[cur][0][wm + mf * 16 + fr][fq * 8];
#pragma unroll
    for (int nf = 0; nf < 4; ++nf) bgf[nf]  = *(const bf16x8*)&lds[cur][1][wn + nf * 16 + fr][fq * 8];
#pragma unroll
    for (int nf = 0; nf < 4; ++nf) buf_[nf] = *(const bf16x8*)&lds[cur][2][wn + nf * 16 + fr][fq * 8];
#pragma unroll
    for (int mf = 0; mf < 4; ++mf)
#pragma unroll
      for (int nf = 0; nf < 4; ++nf) {
        gacc[mf][nf] = __builtin_amdgcn_mfma_f32_16x16x32_bf16(af[mf], bgf[nf],  gacc[mf][nf], 0, 0, 0);
        uacc[mf][nf] = __builtin_amdgcn_mfma_f32_16x16x32_bf16(af[mf], buf_[nf], uacc[mf][nf], 0, 0, 0);
      }
    __syncthreads();
  }
#undef STAGE1

#pragma unroll
  for (int mf = 0; mf < 4; ++mf)
#pragma unroll
    for (int i = 0; i < 4; ++i) {
      int rloc = wm + mf * 16 + fq * 4 + i;
      int rseg = ts + rloc;
      if (rseg < segN) {
        size_t base = (size_t)(segBase + rseg) * H_DIM + ncol0 + wn;
#pragma unroll
        for (int nf = 0; nf < 4; ++nf) {
          float g = gacc[mf][nf][i], u = uacc[mf][nf][i];
          float h = g / (1.f + __expf(-g)) * u;   // silu(g)*u
          hbuf[base + nf * 16 + fr] = f2bf(h);
        }
      }
    }
}

// ---------------- GEMM2: counted-vmcnt 256x256x64 schedule (T3+T4+T2+T5) ------
// Per K-tile: plain-C ds_read+MFMA region; lgkmcnt(0)+barrier (all reads of
// buf[cur] done); stage kt+2 into buf[cur]; vmcnt(8) counted (kt+1 landed,
// kt+2 stays in flight ACROSS the barrier); barrier. Never vmcnt(0) in
// steady state. T2 swizzle: linear gload_lds dest + inverse-swizzled global
// source + swizzled ds_read (rule 21, chunk ^= row&7).
__launch_bounds__(512, 2)
__global__ void gemm2_kernel(const unsigned short* __restrict__ hbuf,
                             const unsigned short* __restrict__ wdb,
                             const int* __restrict__ cnt,
                             const float* __restrict__ wts,
                             unsigned short* __restrict__ wout) {
  TileInfo ti;
  if (!tile_lookup2(cnt, blockIdx.y, ti)) return;
  const int tid = threadIdx.x;
  const int e = ti.e, ts = ti.ts, segBase = ti.segBase, segN = ti.segN;
  const int ncol0 = blockIdx.x * BN2T;

  __shared__ unsigned short ldsA[2][BM2 * BK2];   // 64 KiB
  __shared__ unsigned short ldsB[2][BN2T * BK2];  // 64 KiB  -> 128 KiB total

  const unsigned short* wde = wdb + (size_t)e * DOUT_ * H_DIM;

  // Staging geometry: 4 issues per operand per K-tile; issue i covers LDS
  // chunk gch = i*512+tid (16 B each, linear dest = wave-uniform + lane*16).
  const unsigned short* asrc[4];
  const unsigned short* bsrc[4];
  int sdst[4];
#pragma unroll
  for (int i = 0; i < 4; ++i) {
    int gch = i * 512 + tid;
    int r = gch >> 3;                      // tile row 0..255
    int c = (gch & 7) ^ (r & 7);           // inverse-swizzled source chunk
    int ar = ts + r; if (ar >= segN) ar = segN - 1;
    asrc[i] = hbuf + (size_t)(segBase + ar) * H_DIM + c * 8;
    bsrc[i] = wde + (size_t)(ncol0 + r) * H_DIM + c * 8;
    sdst[i] = gch * 8;                     // element offset (linear)
  }

#define STG2(buf, k0) do { \
    _Pragma("unroll") for (int i_ = 0; i_ < 4; ++i_) gload16(asrc[i_] + (k0), &ldsA[buf][sdst[i_]]); \
    _Pragma("unroll") for (int i_ = 0; i_ < 4; ++i_) gload16(bsrc[i_] + (k0), &ldsB[buf][sdst[i_]]); \
  } while (0)

  const int lane = tid & 63, wid = tid >> 6;
  const int wr = wid >> 2, wc = wid & 3;   // 2M x 4N waves; per-wave 128x64
  const int fr = lane & 15, fq = lane >> 4;

  // Swizzled frag-read offsets (elements), kt-invariant, statically indexed.
  int aoff[8][2], boff[4][2];
#pragma unroll
  for (int mf = 0; mf < 8; ++mf) {
    int row = wr * 128 + mf * 16 + fr;
#pragma unroll
    for (int kk = 0; kk < 2; ++kk)
      aoff[mf][kk] = row * BK2 + (((kk * 4 + fq) ^ (row & 7)) * 8);
  }
#pragma unroll
  for (int nf = 0; nf < 4; ++nf) {
    int row = wc * 64 + nf * 16 + fr;
#pragma unroll
    for (int kk = 0; kk < 2; ++kk)
      boff[nf][kk] = row * BK2 + (((kk * 4 + fq) ^ (row & 7)) * 8);
  }

  f32x4 acc[8][4] = {};

  STG2(0, 0);
  STG2(1, BK2);
  asm volatile("s_waitcnt vmcnt(8)" ::: "memory");   // tile 0 landed (per wave)
  __builtin_amdgcn_sched_barrier(0);
  __builtin_amdgcn_s_barrier();                      // all waves confirmed

  for (int kt = 0; kt < NT2; ++kt) {
    const int cur = kt & 1;
    const unsigned short* A = ldsA[cur];
    const unsigned short* B = ldsB[cur];
#pragma unroll
    for (int kk = 0; kk < 2; ++kk) {
      bf16x8 a[8], b[4];
#pragma unroll
      for (int nf = 0; nf < 4; ++nf) b[nf] = *(const bf16x8*)&B[boff[nf][kk]];
#pragma unroll
      for (int mf = 0; mf < 8; ++mf) a[mf] = *(const bf16x8*)&A[aoff[mf][kk]];
      __builtin_amdgcn_s_setprio(1);
#pragma unroll
      for (int mf = 0; mf < 8; ++mf)
#pragma unroll
        for (int nf = 0; nf < 4; ++nf)
          acc[mf][nf] = __builtin_amdgcn_mfma_f32_16x16x32_bf16(a[mf], b[nf], acc[mf][nf], 0, 0, 0);
      __builtin_amdgcn_s_setprio(0);
    }
    if (kt + 1 < NT2) {
      asm volatile("s_waitcnt lgkmcnt(0)" ::: "memory");  // our ds_reads of buf[cur] done
      __builtin_amdgcn_sched_barrier(0);
      __builtin_amdgcn_s_barrier();                       // ALL waves done reading buf[cur]
      if (kt + 2 < NT2) {
        STG2(cur, (kt + 2) * BK2);                        // overwrite freed buf[cur]
        asm volatile("s_waitcnt vmcnt(8)" ::: "memory");  // tile kt+1 landed; kt+2 in flight
      } else {
        asm volatile("s_waitcnt vmcnt(0)" ::: "memory");  // tail: drain tile kt+1
      }
      __builtin_amdgcn_sched_barrier(0);
      __builtin_amdgcn_s_barrier();                       // all waves confirmed
    }
  }
#undef STG2

  // epilogue: wout[pos] = bf16(w * acc)
#pragma unroll
  for (int mf = 0; mf < 8; ++mf)
#pragma unroll
    for (int i = 0; i < 4; ++i) {
      int rloc = wr * 128 + mf * 16 + fq * 4 + i;
      int rseg = ts + rloc;
      if (rseg < segN) {
        float w = wts[segBase + rseg];
        unsigned short* obase = wout + (size_t)(segBase + rseg) * DOUT_ + ncol0 + wc * 64;
#pragma unroll
        for (int nf = 0; nf < 4; ++nf)
          obase[nf * 16 + fr] = f2bf(acc[mf][nf][i] * w);
      }
    }
}

// ---------------- combine: out[t] = wout[inv[2t]] + wout[inv[2t+1]] (bf16 in) ----
__global__ void combine_kernel(const unsigned short* __restrict__ wout, const int* __restrict__ inv,
                               float* __restrict__ out) {
  const int total = T_TOK * (DOUT_ / 4);           // 4-elem chunks
  for (int i = blockIdx.x * blockDim.x + threadIdx.x; i < total;
       i += gridDim.x * blockDim.x) {
    int t = i >> 8;                                 // DOUT/4 = 256 chunks per token
    int c4 = (i & 255) << 2;
    int p0 = inv[2 * t], p1 = inv[2 * t + 1];
    ushort4 a = *(const ushort4*)(wout + ((size_t)p0 << 10) + c4);
    ushort4 b = *(const ushort4*)(wout + ((size_t)p1 << 10) + c4);
    float4 r;
    r.x = bf2f(a.x) + bf2f(b.x);
    r.y = bf2f(a.y) + bf2f(b.y);
    r.z = bf2f(a.z) + bf2f(b.z);
    r.w = bf2f(a.w) + bf2f(b.w);
    *(float4*)(out + ((size_t)t << 10) + c4) = r;
  }
}

// ---------------- launch ----------------
extern "C" void kernel_launch(void* const* d_in, const int* in_sizes, int n_in,
                              void* d_out, int out_size, void* d_ws, size_t ws_size,
                              hipStream_t stream) {
  const float* x   = (const float*)d_in[0];
  const int*   idx = (const int*)d_in[1];
  const float* tkw = (const float*)d_in[2];
  const float* wg  = (const float*)d_in[3];
  const float* wu  = (const float*)d_in[4];
  const float* wd  = (const float*)d_in[5];
  float* out = (float*)d_out;

  char* p = (char*)d_ws;
  // wout (bf16, 33.5 MB) aliases xb+wgb: dead after gemm1, rewritten by
  // convert at the start of every call -> deterministic.
  unsigned short* wout = (unsigned short*)p;
  unsigned short* xb   = (unsigned short*)p; p += (size_t)T_TOK * D_IN * 2;
  unsigned short* wgb  = (unsigned short*)p; p += (size_t)NEXP * H_DIM * D_IN * 2;
  unsigned short* wub  = (unsigned short*)p; p += (size_t)NEXP * H_DIM * D_IN * 2;
  unsigned short* wdb  = (unsigned short*)p; p += (size_t)NEXP * DOUT_ * H_DIM * 2;
  unsigned short* hbuf = (unsigned short*)p; p += (size_t)NPAIR * H_DIM * 2;
  int*   rows = (int*)p;   p += NPAIR * 4;
  float* wts  = (float*)p; p += NPAIR * 4;
  int*   inv  = (int*)p;   p += NPAIR * 4;
  int* meta = (int*)p;                 // cnt[8] fill[8]
  int* cnt = meta;
  int* fill = meta + 8;

  hipMemsetAsync(meta, 0, 64, stream);                       // cnt + fill

  convert_kernel<<<2048, 256, 0, stream>>>(x, wg, wu, wd, xb, wgb, wub, wdb);
  count_kernel<<<NPAIR / 256, 256, 0, stream>>>(idx, cnt);
  fill_kernel<<<NPAIR / 256, 256, 0, stream>>>(idx, tkw, cnt, fill, rows, wts, inv);
  gemm1_kernel<<<dim3(H_DIM / BN, MAX_TILES), 256, 0, stream>>>(xb, wgb, wub, cnt, rows, hbuf);
  gemm2_kernel<<<dim3(DOUT_ / BN2T, MAX_TILES2), 512, 0, stream>>>(hbuf, wdb, cnt, wts, wout);
  combine_kernel<<<2048, 256, 0, stream>>>(wout, inv, out);
}

// Round 8
// 505.695 us; speedup vs baseline: 1.0164x; 1.0164x over previous
//
#include <hip/hip_runtime.h>

#define T_TOK 8192
#define D_IN  1024
#define H_DIM 2048
#define DOUT_ 1024
#define NEXP  8
#define NPAIR 16384
#define BM 128
#define BN 128
#define BK 32
#define MAX_TILES 136
#define NWG1 (16 * MAX_TILES)   // 2176 = 8*272
#define NWG2 (8 * MAX_TILES)    // 1088 = 8*136

using bf16x8 = __attribute__((ext_vector_type(8))) __bf16;
using f32x4  = __attribute__((ext_vector_type(4))) float;
using us8    = __attribute__((ext_vector_type(8))) unsigned short;

__device__ __forceinline__ unsigned short f2bf(float f) {
  unsigned int u = __float_as_uint(f);
  u += 0x7FFFu + ((u >> 16) & 1u);   // RNE
  return (unsigned short)(u >> 16);
}

__device__ __forceinline__ float bf2f(unsigned short b) {
  return __uint_as_float((unsigned int)b << 16);
}

__device__ __forceinline__ void gload16(const void* g, void* l) {
  __builtin_amdgcn_global_load_lds(
      (const __attribute__((address_space(1))) void*)g,
      (__attribute__((address_space(3))) void*)l, 16, 0, 0);
}

// Derive this block's (expert, tileStart, segBase, segN) from cnt[8] in
// registers (no meta-table cross-kernel communication).
struct TileInfo { int e, ts, segBase, segN; };
__device__ __forceinline__ bool tile_lookup(const int* __restrict__ cnt, int by, TileInfo& ti) {
  int tp = 0, acc = 0;
  ti.e = -1;
#pragma unroll
  for (int e = 0; e < NEXP; ++e) {
    int c = cnt[e];
    int nt = (c + BM - 1) / BM;
    if (ti.e < 0 && by < tp + nt) { ti.e = e; ti.ts = (by - tp) * BM; ti.segBase = acc; ti.segN = c; }
    tp += nt; acc += c;
  }
  return ti.e >= 0;
}

// ---------------- conversion fp32 -> bf16 (16B loads AND 16B stores) --------
// All region boundaries are multiples of 2048 elements, so the region branch
// is uniform within a block (no divergence).
__global__ void convert_kernel(const float* __restrict__ x, const float* __restrict__ wg,
                               const float* __restrict__ wu, const float* __restrict__ wd,
                               unsigned short* __restrict__ xb, unsigned short* __restrict__ wgb,
                               unsigned short* __restrict__ wub, unsigned short* __restrict__ wdb) {
  const long long nx = (long long)T_TOK * D_IN;
  const long long nw = (long long)NEXP * H_DIM * D_IN;
  const long long nd = (long long)NEXP * DOUT_ * H_DIM;
  const long long tot8 = (nx + 2 * nw + nd) >> 3;
  for (long long i = (long long)blockIdx.x * blockDim.x + threadIdx.x; i < tot8;
       i += (long long)gridDim.x * blockDim.x) {
    long long e = i << 3;
    const float* s; unsigned short* d; long long o;
    if (e < nx)              { s = x;  d = xb;  o = e; }
    else if (e < nx + nw)    { s = wg; d = wgb; o = e - nx; }
    else if (e < nx + 2*nw)  { s = wu; d = wub; o = e - nx - nw; }
    else                     { s = wd; d = wdb; o = e - nx - 2*nw; }
    float4 v0 = *(const float4*)(s + o);
    float4 v1 = *(const float4*)(s + o + 4);
    us8 b;
    b[0] = f2bf(v0.x); b[1] = f2bf(v0.y); b[2] = f2bf(v0.z); b[3] = f2bf(v0.w);
    b[4] = f2bf(v1.x); b[5] = f2bf(v1.y); b[6] = f2bf(v1.z); b[7] = f2bf(v1.w);
    *(us8*)(d + o) = b;
  }
}

// ---------------- dispatch build ----------------
__global__ void count_kernel(const int* __restrict__ idx, int* __restrict__ cnt) {
  int i = blockIdx.x * blockDim.x + threadIdx.x;
  if (i < NPAIR) atomicAdd(&cnt[idx[i]], 1);
}

__global__ void fill_kernel(const int* __restrict__ idx, const float* __restrict__ w,
                            const int* __restrict__ cnt, int* __restrict__ fill,
                            int* __restrict__ rows, float* __restrict__ wts,
                            int* __restrict__ inv) {
  int i = blockIdx.x * blockDim.x + threadIdx.x;
  if (i < NPAIR) {
    int e = idx[i];
    int base = 0, acc = 0;
#pragma unroll
    for (int k = 0; k < NEXP; ++k) {
      if (k == e) base = acc;
      acc += cnt[k];
    }
    int p = atomicAdd(&fill[e], 1);
    int pos = base + p;
    rows[pos] = i >> 1;       // token id (K=2)
    wts[pos] = w[i];
    inv[i] = pos;
  }
}

// ---------------- GEMM1: h = silu(x@Wg^T) * (x@Wu^T) ----------------
// (256,2) / VGPR 100 is the proven point (207 us). Only delta: T1 XCD-swizzle
// of the block id (grid-order only; correctness-neutral; bijective 2176=8*272).
__launch_bounds__(256, 2)
__global__ void gemm1_kernel(const unsigned short* __restrict__ xb,
                             const unsigned short* __restrict__ wgb,
                             const unsigned short* __restrict__ wub,
                             const int* __restrict__ cnt, const int* __restrict__ rows,
                             unsigned short* __restrict__ hbuf) {
  const int lid = blockIdx.y * 16 + blockIdx.x;
  const int sid = (lid & 7) * (NWG1 / 8) + (lid >> 3);   // chunked XCD swizzle
  const int bx = sid & 15, by = sid >> 4;

  TileInfo ti;
  if (!tile_lookup(cnt, by, ti)) return;
  const int tid = threadIdx.x;
  const int e = ti.e, ts = ti.ts, segBase = ti.segBase, segN = ti.segN;
  const int ncol0 = bx * BN;

  __shared__ unsigned short lds[2][3][BM][BK];   // A, Bg, Bu double-buffered: 48 KiB
  __shared__ int rows_s[BM];

  if (tid < BM) {
    int r = ts + tid;
    rows_s[tid] = rows[segBase + (r < segN ? r : 0)];
  }
  __syncthreads();

  const int r0 = tid >> 2, r1 = 64 + (tid >> 2);
  const int kq = (tid & 3) * 8;   // bf16 elements
  const int tok0 = rows_s[r0], tok1 = rows_s[r1];
  const unsigned short* ag0 = xb + (size_t)tok0 * D_IN + kq;
  const unsigned short* ag1 = xb + (size_t)tok1 * D_IN + kq;
  const unsigned short* wge = wgb + (size_t)e * H_DIM * D_IN;
  const unsigned short* wue = wub + (size_t)e * H_DIM * D_IN;
  const unsigned short* bg0 = wge + (size_t)(ncol0 + r0) * D_IN + kq;
  const unsigned short* bg1 = wge + (size_t)(ncol0 + r1) * D_IN + kq;
  const unsigned short* bu0 = wue + (size_t)(ncol0 + r0) * D_IN + kq;
  const unsigned short* bu1 = wue + (size_t)(ncol0 + r1) * D_IN + kq;

#define STAGE1(b, k0) do { \
    gload16(ag0 + (k0), &lds[b][0][r0][kq]); \
    gload16(ag1 + (k0), &lds[b][0][r1][kq]); \
    gload16(bg0 + (k0), &lds[b][1][r0][kq]); \
    gload16(bg1 + (k0), &lds[b][1][r1][kq]); \
    gload16(bu0 + (k0), &lds[b][2][r0][kq]); \
    gload16(bu1 + (k0), &lds[b][2][r1][kq]); \
  } while (0)

  f32x4 gacc[4][4] = {};
  f32x4 uacc[4][4] = {};
  const int lane = tid & 63, wid = tid >> 6;
  const int wm = (wid >> 1) * 64, wn = (wid & 1) * 64;
  const int fr = lane & 15, fq = lane >> 4;

  STAGE1(0, 0);
  __syncthreads();
  for (int kt = 0; kt < D_IN / BK; ++kt) {
    const int cur = kt & 1;
    if (kt + 1 < D_IN / BK) STAGE1(cur ^ 1, (kt + 1) * BK);
    bf16x8 af[4], bgf[4], buf_[4];
#pragma unroll
    for (int mf = 0; mf < 4; ++mf) af[mf]   = *(const bf16x8*)&lds[cur][0][wm + mf * 16 + fr][fq * 8];
#pragma unroll
    for (int nf = 0; nf < 4; ++nf) bgf[nf]  = *(const bf16x8*)&lds[cur][1][wn + nf * 16 + fr][fq * 8];
#pragma unroll
    for (int nf = 0; nf < 4; ++nf) buf_[nf] = *(const bf16x8*)&lds[cur][2][wn + nf * 16 + fr][fq * 8];
#pragma unroll
    for (int mf = 0; mf < 4; ++mf)
#pragma unroll
      for (int nf = 0; nf < 4; ++nf) {
        gacc[mf][nf] = __builtin_amdgcn_mfma_f32_16x16x32_bf16(af[mf], bgf[nf],  gacc[mf][nf], 0, 0, 0);
        uacc[mf][nf] = __builtin_amdgcn_mfma_f32_16x16x32_bf16(af[mf], buf_[nf], uacc[mf][nf], 0, 0, 0);
      }
    __syncthreads();
  }
#undef STAGE1

#pragma unroll
  for (int mf = 0; mf < 4; ++mf)
#pragma unroll
    for (int i = 0; i < 4; ++i) {
      int rloc = wm + mf * 16 + fq * 4 + i;
      int rseg = ts + rloc;
      if (rseg < segN) {
        size_t base = (size_t)(segBase + rseg) * H_DIM + ncol0 + wn;
#pragma unroll
        for (int nf = 0; nf < 4; ++nf) {
          float g = gacc[mf][nf][i], u = uacc[mf][nf][i];
          float h = g / (1.f + __expf(-g)) * u;   // silu(g)*u
          hbuf[base + nf * 16 + fr] = f2bf(h);
        }
      }
    }
}

// ---------------- GEMM2: wout[pos] = w * (h @ Wd^T) ----------------
// Round-6 proven config: BN=128 @ (256,4), bf16 wout. Only delta: T1 swizzle
// (bijective 1088=8*136).
__launch_bounds__(256, 4)
__global__ void gemm2_kernel(const unsigned short* __restrict__ hbuf,
                             const unsigned short* __restrict__ wdb,
                             const int* __restrict__ cnt,
                             const float* __restrict__ wts, unsigned short* __restrict__ wout) {
  const int lid = blockIdx.y * 8 + blockIdx.x;
  const int sid = (lid & 7) * (NWG2 / 8) + (lid >> 3);
  const int bx = sid & 7, by = sid >> 3;

  TileInfo ti;
  if (!tile_lookup(cnt, by, ti)) return;
  const int tid = threadIdx.x;
  const int e = ti.e, ts = ti.ts, segBase = ti.segBase, segN = ti.segN;
  const int ncol0 = bx * BN;

  __shared__ unsigned short lds[2][2][BM][BK];   // 32 KiB

  const int r0 = tid >> 2, r1 = 64 + (tid >> 2);
  const int kq = (tid & 3) * 8;
  int ar0 = ts + r0; if (ar0 >= segN) ar0 = segN - 1;
  int ar1 = ts + r1; if (ar1 >= segN) ar1 = segN - 1;
  const unsigned short* ag0 = hbuf + (size_t)(segBase + ar0) * H_DIM + kq;
  const unsigned short* ag1 = hbuf + (size_t)(segBase + ar1) * H_DIM + kq;
  const unsigned short* wde = wdb + (size_t)e * DOUT_ * H_DIM;
  const unsigned short* bg0 = wde + (size_t)(ncol0 + r0) * H_DIM + kq;
  const unsigned short* bg1 = wde + (size_t)(ncol0 + r1) * H_DIM + kq;

#define STAGE2(b, k0) do { \
    gload16(ag0 + (k0), &lds[b][0][r0][kq]); \
    gload16(ag1 + (k0), &lds[b][0][r1][kq]); \
    gload16(bg0 + (k0), &lds[b][1][r0][kq]); \
    gload16(bg1 + (k0), &lds[b][1][r1][kq]); \
  } while (0)

  f32x4 acc[4][4] = {};
  const int lane = tid & 63, wid = tid >> 6;
  const int wm = (wid >> 1) * 64, wn = (wid & 1) * 64;
  const int fr = lane & 15, fq = lane >> 4;

  STAGE2(0, 0);
  __syncthreads();
  for (int kt = 0; kt < H_DIM / BK; ++kt) {
    const int cur = kt & 1;
    if (kt + 1 < H_DIM / BK) STAGE2(cur ^ 1, (kt + 1) * BK);
    bf16x8 af[4], bf[4];
#pragma unroll
    for (int mf = 0; mf < 4; ++mf) af[mf] = *(const bf16x8*)&lds[cur][0][wm + mf * 16 + fr][fq * 8];
#pragma unroll
    for (int nf = 0; nf < 4; ++nf) bf[nf] = *(const bf16x8*)&lds[cur][1][wn + nf * 16 + fr][fq * 8];
#pragma unroll
    for (int mf = 0; mf < 4; ++mf)
#pragma unroll
      for (int nf = 0; nf < 4; ++nf)
        acc[mf][nf] = __builtin_amdgcn_mfma_f32_16x16x32_bf16(af[mf], bf[nf], acc[mf][nf], 0, 0, 0);
    __syncthreads();
  }
#undef STAGE2

#pragma unroll
  for (int mf = 0; mf < 4; ++mf)
#pragma unroll
    for (int i = 0; i < 4; ++i) {
      int rloc = wm + mf * 16 + fq * 4 + i;
      int rseg = ts + rloc;
      if (rseg < segN) {
        float w = wts[segBase + rseg];
        unsigned short* obase = wout + (size_t)(segBase + rseg) * DOUT_ + ncol0 + wn;
#pragma unroll
        for (int nf = 0; nf < 4; ++nf)
          obase[nf * 16 + fr] = f2bf(acc[mf][nf][i] * w);
      }
    }
}

// ---------------- combine: out[t] = wout[inv[2t]] + wout[inv[2t+1]] (bf16 in) ----
__global__ void combine_kernel(const unsigned short* __restrict__ wout, const int* __restrict__ inv,
                               float* __restrict__ out) {
  const int total = T_TOK * (DOUT_ / 4);           // 4-elem chunks
  for (int i = blockIdx.x * blockDim.x + threadIdx.x; i < total;
       i += gridDim.x * blockDim.x) {
    int t = i >> 8;                                 // DOUT/4 = 256 chunks per token
    int c4 = (i & 255) << 2;
    int p0 = inv[2 * t], p1 = inv[2 * t + 1];
    ushort4 a = *(const ushort4*)(wout + ((size_t)p0 << 10) + c4);
    ushort4 b = *(const ushort4*)(wout + ((size_t)p1 << 10) + c4);
    float4 r;
    r.x = bf2f(a.x) + bf2f(b.x);
    r.y = bf2f(a.y) + bf2f(b.y);
    r.z = bf2f(a.z) + bf2f(b.z);
    r.w = bf2f(a.w) + bf2f(b.w);
    *(float4*)(out + ((size_t)t << 10) + c4) = r;
  }
}

// ---------------- launch ----------------
extern "C" void kernel_launch(void* const* d_in, const int* in_sizes, int n_in,
                              void* d_out, int out_size, void* d_ws, size_t ws_size,
                              hipStream_t stream) {
  const float* x   = (const float*)d_in[0];
  const int*   idx = (const int*)d_in[1];
  const float* tkw = (const float*)d_in[2];
  const float* wg  = (const float*)d_in[3];
  const float* wu  = (const float*)d_in[4];
  const float* wd  = (const float*)d_in[5];
  float* out = (float*)d_out;

  char* p = (char*)d_ws;
  // wout (bf16, 33.5 MB) aliases xb+wgb: dead after gemm1, rewritten by
  // convert at the start of every call -> deterministic.
  unsigned short* wout = (unsigned short*)p;
  unsigned short* xb   = (unsigned short*)p; p += (size_t)T_TOK * D_IN * 2;
  unsigned short* wgb  = (unsigned short*)p; p += (size_t)NEXP * H_DIM * D_IN * 2;
  unsigned short* wub  = (unsigned short*)p; p += (size_t)NEXP * H_DIM * D_IN * 2;
  unsigned short* wdb  = (unsigned short*)p; p += (size_t)NEXP * DOUT_ * H_DIM * 2;
  unsigned short* hbuf = (unsigned short*)p; p += (size_t)NPAIR * H_DIM * 2;
  int*   rows = (int*)p;   p += NPAIR * 4;
  float* wts  = (float*)p; p += NPAIR * 4;
  int*   inv  = (int*)p;   p += NPAIR * 4;
  int* meta = (int*)p;                 // cnt[8] fill[8]
  int* cnt = meta;
  int* fill = meta + 8;

  hipMemsetAsync(meta, 0, 64, stream);                       // cnt + fill

  convert_kernel<<<2048, 256, 0, stream>>>(x, wg, wu, wd, xb, wgb, wub, wdb);
  count_kernel<<<NPAIR / 256, 256, 0, stream>>>(idx, cnt);
  fill_kernel<<<NPAIR / 256, 256, 0, stream>>>(idx, tkw, cnt, fill, rows, wts, inv);
  gemm1_kernel<<<dim3(16, MAX_TILES), 256, 0, stream>>>(xb, wgb, wub, cnt, rows, hbuf);
  gemm2_kernel<<<dim3(8, MAX_TILES), 256, 0, stream>>>(hbuf, wdb, cnt, wts, wout);
  combine_kernel<<<2048, 256, 0, stream>>>(wout, inv, out);
}

// Round 9
// 395.583 us; speedup vs baseline: 1.2994x; 1.2784x over previous
//
#include <hip/hip_runtime.h>

#define T_TOK 8192
#define D_IN  1024
#define H_DIM 2048
#define DOUT_ 1024
#define NEXP  8
#define NPAIR 16384
#define BM 128
#define BN 128
#define BK 32
#define MAX_TILES 136

using bf16x8 = __attribute__((ext_vector_type(8))) __bf16;
using f32x4  = __attribute__((ext_vector_type(4))) float;
using us8    = __attribute__((ext_vector_type(8))) unsigned short;

__device__ __forceinline__ unsigned short f2bf(float f) {
  unsigned int u = __float_as_uint(f);
  u += 0x7FFFu + ((u >> 16) & 1u);   // RNE
  return (unsigned short)(u >> 16);
}

__device__ __forceinline__ float bf2f(unsigned short b) {
  return __uint_as_float((unsigned int)b << 16);
}

__device__ __forceinline__ void gload16(const void* g, void* l) {
  __builtin_amdgcn_global_load_lds(
      (const __attribute__((address_space(1))) void*)g,
      (__attribute__((address_space(3))) void*)l, 16, 0, 0);
}

// Derive this block's (expert, tileStart, segBase, segN) from cnt[8] in
// registers (no meta-table cross-kernel communication).
struct TileInfo { int e, ts, segBase, segN; };
__device__ __forceinline__ bool tile_lookup(const int* __restrict__ cnt, int by, TileInfo& ti) {
  int tp = 0, acc = 0;
  ti.e = -1;
#pragma unroll
  for (int e = 0; e < NEXP; ++e) {
    int c = cnt[e];
    int nt = (c + BM - 1) / BM;
    if (ti.e < 0 && by < tp + nt) { ti.e = e; ti.ts = (by - tp) * BM; ti.segBase = acc; ti.segN = c; }
    tp += nt; acc += c;
  }
  return ti.e >= 0;
}

// ---------------- conversion fp32 -> bf16 (16B loads AND stores; proven) ----
__global__ void convert_kernel(const float* __restrict__ x, const float* __restrict__ wg,
                               const float* __restrict__ wu, const float* __restrict__ wd,
                               unsigned short* __restrict__ xb, unsigned short* __restrict__ wgb,
                               unsigned short* __restrict__ wub, unsigned short* __restrict__ wdb) {
  const long long nx = (long long)T_TOK * D_IN;
  const long long nw = (long long)NEXP * H_DIM * D_IN;
  const long long nd = (long long)NEXP * DOUT_ * H_DIM;
  const long long tot8 = (nx + 2 * nw + nd) >> 3;
  for (long long i = (long long)blockIdx.x * blockDim.x + threadIdx.x; i < tot8;
       i += (long long)gridDim.x * blockDim.x) {
    long long e = i << 3;
    const float* s; unsigned short* d; long long o;
    if (e < nx)              { s = x;  d = xb;  o = e; }
    else if (e < nx + nw)    { s = wg; d = wgb; o = e - nx; }
    else if (e < nx + 2*nw)  { s = wu; d = wub; o = e - nx - nw; }
    else                     { s = wd; d = wdb; o = e - nx - 2*nw; }
    float4 v0 = *(const float4*)(s + o);
    float4 v1 = *(const float4*)(s + o + 4);
    us8 b;
    b[0] = f2bf(v0.x); b[1] = f2bf(v0.y); b[2] = f2bf(v0.z); b[3] = f2bf(v0.w);
    b[4] = f2bf(v1.x); b[5] = f2bf(v1.y); b[6] = f2bf(v1.z); b[7] = f2bf(v1.w);
    *(us8*)(d + o) = b;
  }
}

// ---------------- dispatch build: single block, LDS atomics ----------------
// Replaces count_kernel + fill_kernel (2x 16384 GLOBAL atomicAdds on 8
// addresses = serialized L2 round-trips) with LDS atomics in one block.
// Output values are permutation-invariant (each pos's value depends only on
// its pair), so LDS-atomic ordering does not affect determinism.
__global__ void dispatch_kernel(const int* __restrict__ idx, const float* __restrict__ w,
                                int* __restrict__ cnt, int* __restrict__ rows,
                                float* __restrict__ wts, int* __restrict__ inv) {
  __shared__ int hist[NEXP];
  __shared__ int base_s[NEXP];
  __shared__ int fill_s[NEXP];
  const int tid = threadIdx.x;   // 1024
  if (tid < NEXP) hist[tid] = 0;
  __syncthreads();
  for (int i = tid; i < NPAIR; i += 1024)
    atomicAdd(&hist[idx[i]], 1);
  __syncthreads();
  if (tid == 0) {
    int acc = 0;
#pragma unroll
    for (int e = 0; e < NEXP; ++e) { base_s[e] = acc; cnt[e] = hist[e]; acc += hist[e]; }
  }
  if (tid < NEXP) fill_s[tid] = 0;
  __syncthreads();
  for (int i = tid; i < NPAIR; i += 1024) {
    int e = idx[i];
    int p = atomicAdd(&fill_s[e], 1);
    int pos = base_s[e] + p;
    rows[pos] = i >> 1;       // token id (K=2)
    wts[pos] = w[i];
    inv[i] = pos;
  }
}

// ---------------- GEMM1: h = silu(x@Wg^T) * (x@Wu^T) ----------------
// (256,2) / VGPR 100 / default dispatch order is the proven point (206 us).
// T1 XCD-swizzle REGRESSES here (+12 us, FETCH +17%): per-XCD chunks stream
// an 8.4 MB expert panel through 4 MB L2. FROZEN.
__launch_bounds__(256, 2)
__global__ void gemm1_kernel(const unsigned short* __restrict__ xb,
                             const unsigned short* __restrict__ wgb,
                             const unsigned short* __restrict__ wub,
                             const int* __restrict__ cnt, const int* __restrict__ rows,
                             unsigned short* __restrict__ hbuf) {
  TileInfo ti;
  if (!tile_lookup(cnt, blockIdx.y, ti)) return;
  const int tid = threadIdx.x;
  const int e = ti.e, ts = ti.ts, segBase = ti.segBase, segN = ti.segN;
  const int ncol0 = blockIdx.x * BN;

  __shared__ unsigned short lds[2][3][BM][BK];   // A, Bg, Bu double-buffered: 48 KiB
  __shared__ int rows_s[BM];

  if (tid < BM) {
    int r = ts + tid;
    rows_s[tid] = rows[segBase + (r < segN ? r : 0)];
  }
  __syncthreads();

  const int r0 = tid >> 2, r1 = 64 + (tid >> 2);
  const int kq = (tid & 3) * 8;   // bf16 elements
  const int tok0 = rows_s[r0], tok1 = rows_s[r1];
  const unsigned short* ag0 = xb + (size_t)tok0 * D_IN + kq;
  const unsigned short* ag1 = xb + (size_t)tok1 * D_IN + kq;
  const unsigned short* wge = wgb + (size_t)e * H_DIM * D_IN;
  const unsigned short* wue = wub + (size_t)e * H_DIM * D_IN;
  const unsigned short* bg0 = wge + (size_t)(ncol0 + r0) * D_IN + kq;
  const unsigned short* bg1 = wge + (size_t)(ncol0 + r1) * D_IN + kq;
  const unsigned short* bu0 = wue + (size_t)(ncol0 + r0) * D_IN + kq;
  const unsigned short* bu1 = wue + (size_t)(ncol0 + r1) * D_IN + kq;

#define STAGE1(b, k0) do { \
    gload16(ag0 + (k0), &lds[b][0][r0][kq]); \
    gload16(ag1 + (k0), &lds[b][0][r1][kq]); \
    gload16(bg0 + (k0), &lds[b][1][r0][kq]); \
    gload16(bg1 + (k0), &lds[b][1][r1][kq]); \
    gload16(bu0 + (k0), &lds[b][2][r0][kq]); \
    gload16(bu1 + (k0), &lds[b][2][r1][kq]); \
  } while (0)

  f32x4 gacc[4][4] = {};
  f32x4 uacc[4][4] = {};
  const int lane = tid & 63, wid = tid >> 6;
  const int wm = (wid >> 1) * 64, wn = (wid & 1) * 64;
  const int fr = lane & 15, fq = lane >> 4;

  STAGE1(0, 0);
  __syncthreads();
  for (int kt = 0; kt < D_IN / BK; ++kt) {
    const int cur = kt & 1;
    if (kt + 1 < D_IN / BK) STAGE1(cur ^ 1, (kt + 1) * BK);
    bf16x8 af[4], bgf[4], buf_[4];
#pragma unroll
    for (int mf = 0; mf < 4; ++mf) af[mf]   = *(const bf16x8*)&lds[cur][0][wm + mf * 16 + fr][fq * 8];
#pragma unroll
    for (int nf = 0; nf < 4; ++nf) bgf[nf]  = *(const bf16x8*)&lds[cur][1][wn + nf * 16 + fr][fq * 8];
#pragma unroll
    for (int nf = 0; nf < 4; ++nf) buf_[nf] = *(const bf16x8*)&lds[cur][2][wn + nf * 16 + fr][fq * 8];
#pragma unroll
    for (int mf = 0; mf < 4; ++mf)
#pragma unroll
      for (int nf = 0; nf < 4; ++nf) {
        gacc[mf][nf] = __builtin_amdgcn_mfma_f32_16x16x32_bf16(af[mf], bgf[nf],  gacc[mf][nf], 0, 0, 0);
        uacc[mf][nf] = __builtin_amdgcn_mfma_f32_16x16x32_bf16(af[mf], buf_[nf], uacc[mf][nf], 0, 0, 0);
      }
    __syncthreads();
  }
#undef STAGE1

#pragma unroll
  for (int mf = 0; mf < 4; ++mf)
#pragma unroll
    for (int i = 0; i < 4; ++i) {
      int rloc = wm + mf * 16 + fq * 4 + i;
      int rseg = ts + rloc;
      if (rseg < segN) {
        size_t base = (size_t)(segBase + rseg) * H_DIM + ncol0 + wn;
#pragma unroll
        for (int nf = 0; nf < 4; ++nf) {
          float g = gacc[mf][nf][i], u = uacc[mf][nf][i];
          float h = g / (1.f + __expf(-g)) * u;   // silu(g)*u
          hbuf[base + nf * 16 + fr] = f2bf(h);
        }
      }
    }
}

// ---------------- GEMM2: wout[pos] = w * (h @ Wd^T) ----------------
// Round-6 proven config: BN=128 @ (256,4), bf16 wout, default dispatch order.
__launch_bounds__(256, 4)
__global__ void gemm2_kernel(const unsigned short* __restrict__ hbuf,
                             const unsigned short* __restrict__ wdb,
                             const int* __restrict__ cnt,
                             const float* __restrict__ wts, unsigned short* __restrict__ wout) {
  TileInfo ti;
  if (!tile_lookup(cnt, blockIdx.y, ti)) return;
  const int tid = threadIdx.x;
  const int e = ti.e, ts = ti.ts, segBase = ti.segBase, segN = ti.segN;
  const int ncol0 = blockIdx.x * BN;

  __shared__ unsigned short lds[2][2][BM][BK];   // 32 KiB

  const int r0 = tid >> 2, r1 = 64 + (tid >> 2);
  const int kq = (tid & 3) * 8;
  int ar0 = ts + r0; if (ar0 >= segN) ar0 = segN - 1;
  int ar1 = ts + r1; if (ar1 >= segN) ar1 = segN - 1;
  const unsigned short* ag0 = hbuf + (size_t)(segBase + ar0) * H_DIM + kq;
  const unsigned short* ag1 = hbuf + (size_t)(segBase + ar1) * H_DIM + kq;
  const unsigned short* wde = wdb + (size_t)e * DOUT_ * H_DIM;
  const unsigned short* bg0 = wde + (size_t)(ncol0 + r0) * H_DIM + kq;
  const unsigned short* bg1 = wde + (size_t)(ncol0 + r1) * H_DIM + kq;

#define STAGE2(b, k0) do { \
    gload16(ag0 + (k0), &lds[b][0][r0][kq]); \
    gload16(ag1 + (k0), &lds[b][0][r1][kq]); \
    gload16(bg0 + (k0), &lds[b][1][r0][kq]); \
    gload16(bg1 + (k0), &lds[b][1][r1][kq]); \
  } while (0)

  f32x4 acc[4][4] = {};
  const int lane = tid & 63, wid = tid >> 6;
  const int wm = (wid >> 1) * 64, wn = (wid & 1) * 64;
  const int fr = lane & 15, fq = lane >> 4;

  STAGE2(0, 0);
  __syncthreads();
  for (int kt = 0; kt < H_DIM / BK; ++kt) {
    const int cur = kt & 1;
    if (kt + 1 < H_DIM / BK) STAGE2(cur ^ 1, (kt + 1) * BK);
    bf16x8 af[4], bf[4];
#pragma unroll
    for (int mf = 0; mf < 4; ++mf) af[mf] = *(const bf16x8*)&lds[cur][0][wm + mf * 16 + fr][fq * 8];
#pragma unroll
    for (int nf = 0; nf < 4; ++nf) bf[nf] = *(const bf16x8*)&lds[cur][1][wn + nf * 16 + fr][fq * 8];
#pragma unroll
    for (int mf = 0; mf < 4; ++mf)
#pragma unroll
      for (int nf = 0; nf < 4; ++nf)
        acc[mf][nf] = __builtin_amdgcn_mfma_f32_16x16x32_bf16(af[mf], bf[nf], acc[mf][nf], 0, 0, 0);
    __syncthreads();
  }
#undef STAGE2

#pragma unroll
  for (int mf = 0; mf < 4; ++mf)
#pragma unroll
    for (int i = 0; i < 4; ++i) {
      int rloc = wm + mf * 16 + fq * 4 + i;
      int rseg = ts + rloc;
      if (rseg < segN) {
        float w = wts[segBase + rseg];
        unsigned short* obase = wout + (size_t)(segBase + rseg) * DOUT_ + ncol0 + wn;
#pragma unroll
        for (int nf = 0; nf < 4; ++nf)
          obase[nf * 16 + fr] = f2bf(acc[mf][nf][i] * w);
      }
    }
}

// ---------------- combine: out[t] = wout[inv[2t]] + wout[inv[2t+1]] (bf16 in) ----
__global__ void combine_kernel(const unsigned short* __restrict__ wout, const int* __restrict__ inv,
                               float* __restrict__ out) {
  const int total = T_TOK * (DOUT_ / 4);           // 4-elem chunks
  for (int i = blockIdx.x * blockDim.x + threadIdx.x; i < total;
       i += gridDim.x * blockDim.x) {
    int t = i >> 8;                                 // DOUT/4 = 256 chunks per token
    int c4 = (i & 255) << 2;
    int p0 = inv[2 * t], p1 = inv[2 * t + 1];
    ushort4 a = *(const ushort4*)(wout + ((size_t)p0 << 10) + c4);
    ushort4 b = *(const ushort4*)(wout + ((size_t)p1 << 10) + c4);
    float4 r;
    r.x = bf2f(a.x) + bf2f(b.x);
    r.y = bf2f(a.y) + bf2f(b.y);
    r.z = bf2f(a.z) + bf2f(b.z);
    r.w = bf2f(a.w) + bf2f(b.w);
    *(float4*)(out + ((size_t)t << 10) + c4) = r;
  }
}

// ---------------- launch ----------------
extern "C" void kernel_launch(void* const* d_in, const int* in_sizes, int n_in,
                              void* d_out, int out_size, void* d_ws, size_t ws_size,
                              hipStream_t stream) {
  const float* x   = (const float*)d_in[0];
  const int*   idx = (const int*)d_in[1];
  const float* tkw = (const float*)d_in[2];
  const float* wg  = (const float*)d_in[3];
  const float* wu  = (const float*)d_in[4];
  const float* wd  = (const float*)d_in[5];
  float* out = (float*)d_out;

  char* p = (char*)d_ws;
  // wout (bf16, 33.5 MB) aliases xb+wgb: dead after gemm1, rewritten by
  // convert at the start of every call -> deterministic.
  unsigned short* wout = (unsigned short*)p;
  unsigned short* xb   = (unsigned short*)p; p += (size_t)T_TOK * D_IN * 2;
  unsigned short* wgb  = (unsigned short*)p; p += (size_t)NEXP * H_DIM * D_IN * 2;
  unsigned short* wub  = (unsigned short*)p; p += (size_t)NEXP * H_DIM * D_IN * 2;
  unsigned short* wdb  = (unsigned short*)p; p += (size_t)NEXP * DOUT_ * H_DIM * 2;
  unsigned short* hbuf = (unsigned short*)p; p += (size_t)NPAIR * H_DIM * 2;
  int*   rows = (int*)p;   p += NPAIR * 4;
  float* wts  = (float*)p; p += NPAIR * 4;
  int*   inv  = (int*)p;   p += NPAIR * 4;
  int*   cnt  = (int*)p;   p += NEXP * 4;

  convert_kernel<<<2048, 256, 0, stream>>>(x, wg, wu, wd, xb, wgb, wub, wdb);
  dispatch_kernel<<<1, 1024, 0, stream>>>(idx, tkw, cnt, rows, wts, inv);
  gemm1_kernel<<<dim3(H_DIM / BN, MAX_TILES), 256, 0, stream>>>(xb, wgb, wub, cnt, rows, hbuf);
  gemm2_kernel<<<dim3(DOUT_ / BN, MAX_TILES), 256, 0, stream>>>(hbuf, wdb, cnt, wts, wout);
  combine_kernel<<<2048, 256, 0, stream>>>(wout, inv, out);
}

// Round 10
// 393.639 us; speedup vs baseline: 1.3058x; 1.0049x over previous
//
#include <hip/hip_runtime.h>

#define T_TOK 8192
#define D_IN  1024
#define H_DIM 2048
#define DOUT_ 1024
#define NEXP  8
#define NPAIR 16384
#define BM 128
#define BN 128
#define BK 32
#define MAX_TILES 136

using bf16x8 = __attribute__((ext_vector_type(8))) __bf16;
using f32x4  = __attribute__((ext_vector_type(4))) float;
using us8    = __attribute__((ext_vector_type(8))) unsigned short;

__device__ __forceinline__ unsigned short f2bf(float f) {
  unsigned int u = __float_as_uint(f);
  u += 0x7FFFu + ((u >> 16) & 1u);   // RNE
  return (unsigned short)(u >> 16);
}

__device__ __forceinline__ float bf2f(unsigned short b) {
  return __uint_as_float((unsigned int)b << 16);
}

__device__ __forceinline__ void gload16(const void* g, void* l) {
  __builtin_amdgcn_global_load_lds(
      (const __attribute__((address_space(1))) void*)g,
      (__attribute__((address_space(3))) void*)l, 16, 0, 0);
}

// Derive this block's (expert, tileStart, segBase, segN) from cnt[8] in
// registers (no meta-table cross-kernel communication).
struct TileInfo { int e, ts, segBase, segN; };
__device__ __forceinline__ bool tile_lookup(const int* __restrict__ cnt, int by, TileInfo& ti) {
  int tp = 0, acc = 0;
  ti.e = -1;
#pragma unroll
  for (int e = 0; e < NEXP; ++e) {
    int c = cnt[e];
    int nt = (c + BM - 1) / BM;
    if (ti.e < 0 && by < tp + nt) { ti.e = e; ti.ts = (by - tp) * BM; ti.segBase = acc; ti.segN = c; }
    tp += nt; acc += c;
  }
  return ti.e >= 0;
}

// ---------------- conversion fp32 -> bf16 (16B loads AND stores; proven) ----
__global__ void convert_kernel(const float* __restrict__ x, const float* __restrict__ wg,
                               const float* __restrict__ wu, const float* __restrict__ wd,
                               unsigned short* __restrict__ xb, unsigned short* __restrict__ wgb,
                               unsigned short* __restrict__ wub, unsigned short* __restrict__ wdb) {
  const long long nx = (long long)T_TOK * D_IN;
  const long long nw = (long long)NEXP * H_DIM * D_IN;
  const long long nd = (long long)NEXP * DOUT_ * H_DIM;
  const long long tot8 = (nx + 2 * nw + nd) >> 3;
  for (long long i = (long long)blockIdx.x * blockDim.x + threadIdx.x; i < tot8;
       i += (long long)gridDim.x * blockDim.x) {
    long long e = i << 3;
    const float* s; unsigned short* d; long long o;
    if (e < nx)              { s = x;  d = xb;  o = e; }
    else if (e < nx + nw)    { s = wg; d = wgb; o = e - nx; }
    else if (e < nx + 2*nw)  { s = wu; d = wub; o = e - nx - nw; }
    else                     { s = wd; d = wdb; o = e - nx - 2*nw; }
    float4 v0 = *(const float4*)(s + o);
    float4 v1 = *(const float4*)(s + o + 4);
    us8 b;
    b[0] = f2bf(v0.x); b[1] = f2bf(v0.y); b[2] = f2bf(v0.z); b[3] = f2bf(v0.w);
    b[4] = f2bf(v1.x); b[5] = f2bf(v1.y); b[6] = f2bf(v1.z); b[7] = f2bf(v1.w);
    *(us8*)(d + o) = b;
  }
}

// ---------------- dispatch build: single block, LDS atomics (proven, -110us) --
__global__ void dispatch_kernel(const int* __restrict__ idx, const float* __restrict__ w,
                                int* __restrict__ cnt, int* __restrict__ rows,
                                float* __restrict__ wts, int* __restrict__ inv) {
  __shared__ int hist[NEXP];
  __shared__ int base_s[NEXP];
  __shared__ int fill_s[NEXP];
  const int tid = threadIdx.x;   // 1024
  if (tid < NEXP) hist[tid] = 0;
  __syncthreads();
  for (int i = tid; i < NPAIR; i += 1024)
    atomicAdd(&hist[idx[i]], 1);
  __syncthreads();
  if (tid == 0) {
    int acc = 0;
#pragma unroll
    for (int e = 0; e < NEXP; ++e) { base_s[e] = acc; cnt[e] = hist[e]; acc += hist[e]; }
  }
  if (tid < NEXP) fill_s[tid] = 0;
  __syncthreads();
  for (int i = tid; i < NPAIR; i += 1024) {
    int e = idx[i];
    int p = atomicAdd(&fill_s[e], 1);
    int pos = base_s[e] + p;
    rows[pos] = i >> 1;       // token id (K=2)
    wts[pos] = w[i];
    inv[i] = pos;
  }
}

// ---------------- GEMM1: h = silu(x@Wg^T) * (x@Wu^T) ----------------
// ROUND-10 CHANGE (only one): triple-buffered LDS + counted vmcnt(6) + raw
// s_barrier. Tile t lives in buf[t%3]; iter kt stages tile kt+2, reads tile
// kt, then vmcnt(6) confirms tile kt+1 (issued 2 phases earlier). The
// global_load_lds queue never drains to 0 in steady state (T4 mechanism).
// Race-freedom: tile kt+2 overwrites buf[(kt-1)%3]; all reads of tile kt-1
// completed before the kt-1 barrier (each wave's lgkmcnt precedes its MFMAs,
// which precede the barrier). Rule-18 sched_barrier(0) brackets all waits.
__launch_bounds__(256, 2)
__global__ void gemm1_kernel(const unsigned short* __restrict__ xb,
                             const unsigned short* __restrict__ wgb,
                             const unsigned short* __restrict__ wub,
                             const int* __restrict__ cnt, const int* __restrict__ rows,
                             unsigned short* __restrict__ hbuf) {
  TileInfo ti;
  if (!tile_lookup(cnt, blockIdx.y, ti)) return;
  const int tid = threadIdx.x;
  const int e = ti.e, ts = ti.ts, segBase = ti.segBase, segN = ti.segN;
  const int ncol0 = blockIdx.x * BN;

  __shared__ unsigned short lds[3][3][BM][BK];   // A, Bg, Bu triple-buffered: 72 KiB
  __shared__ int rows_s[BM];

  if (tid < BM) {
    int r = ts + tid;
    rows_s[tid] = rows[segBase + (r < segN ? r : 0)];
  }
  __syncthreads();

  const int r0 = tid >> 2, r1 = 64 + (tid >> 2);
  const int kq = (tid & 3) * 8;   // bf16 elements
  const int tok0 = rows_s[r0], tok1 = rows_s[r1];
  const unsigned short* ag0 = xb + (size_t)tok0 * D_IN + kq;
  const unsigned short* ag1 = xb + (size_t)tok1 * D_IN + kq;
  const unsigned short* wge = wgb + (size_t)e * H_DIM * D_IN;
  const unsigned short* wue = wub + (size_t)e * H_DIM * D_IN;
  const unsigned short* bg0 = wge + (size_t)(ncol0 + r0) * D_IN + kq;
  const unsigned short* bg1 = wge + (size_t)(ncol0 + r1) * D_IN + kq;
  const unsigned short* bu0 = wue + (size_t)(ncol0 + r0) * D_IN + kq;
  const unsigned short* bu1 = wue + (size_t)(ncol0 + r1) * D_IN + kq;

#define STAGE1(b, k0) do { \
    gload16(ag0 + (k0), &lds[b][0][r0][kq]); \
    gload16(ag1 + (k0), &lds[b][0][r1][kq]); \
    gload16(bg0 + (k0), &lds[b][1][r0][kq]); \
    gload16(bg1 + (k0), &lds[b][1][r1][kq]); \
    gload16(bu0 + (k0), &lds[b][2][r0][kq]); \
    gload16(bu1 + (k0), &lds[b][2][r1][kq]); \
  } while (0)

  f32x4 gacc[4][4] = {};
  f32x4 uacc[4][4] = {};
  const int lane = tid & 63, wid = tid >> 6;
  const int wm = (wid >> 1) * 64, wn = (wid & 1) * 64;
  const int fr = lane & 15, fq = lane >> 4;

  const int NT = D_IN / BK;   // 32
  STAGE1(0, 0);
  STAGE1(1, BK);
  asm volatile("s_waitcnt vmcnt(6)" ::: "memory");   // tile 0 landed; tile 1 in flight
  __builtin_amdgcn_sched_barrier(0);
  __builtin_amdgcn_s_barrier();
  __builtin_amdgcn_sched_barrier(0);

  for (int kt = 0; kt < NT; ++kt) {
    const int cur = kt % 3;
    if (kt + 2 < NT) STAGE1((kt + 2) % 3, (kt + 2) * BK);
    bf16x8 af[4], bgf[4], buf_[4];
#pragma unroll
    for (int mf = 0; mf < 4; ++mf) af[mf]   = *(const bf16x8*)&lds[cur][0][wm + mf * 16 + fr][fq * 8];
#pragma unroll
    for (int nf = 0; nf < 4; ++nf) bgf[nf]  = *(const bf16x8*)&lds[cur][1][wn + nf * 16 + fr][fq * 8];
#pragma unroll
    for (int nf = 0; nf < 4; ++nf) buf_[nf] = *(const bf16x8*)&lds[cur][2][wn + nf * 16 + fr][fq * 8];
#pragma unroll
    for (int mf = 0; mf < 4; ++mf)
#pragma unroll
      for (int nf = 0; nf < 4; ++nf) {
        gacc[mf][nf] = __builtin_amdgcn_mfma_f32_16x16x32_bf16(af[mf], bgf[nf],  gacc[mf][nf], 0, 0, 0);
        uacc[mf][nf] = __builtin_amdgcn_mfma_f32_16x16x32_bf16(af[mf], buf_[nf], uacc[mf][nf], 0, 0, 0);
      }
    if (kt + 1 < NT) {
      if (kt + 2 < NT) {
        asm volatile("s_waitcnt vmcnt(6)" ::: "memory");  // tile kt+1 landed; kt+2 in flight
      } else {
        asm volatile("s_waitcnt vmcnt(0)" ::: "memory");  // tail: confirm last tile
      }
      __builtin_amdgcn_sched_barrier(0);
      __builtin_amdgcn_s_barrier();
      __builtin_amdgcn_sched_barrier(0);
    }
  }
#undef STAGE1

#pragma unroll
  for (int mf = 0; mf < 4; ++mf)
#pragma unroll
    for (int i = 0; i < 4; ++i) {
      int rloc = wm + mf * 16 + fq * 4 + i;
      int rseg = ts + rloc;
      if (rseg < segN) {
        size_t base = (size_t)(segBase + rseg) * H_DIM + ncol0 + wn;
#pragma unroll
        for (int nf = 0; nf < 4; ++nf) {
          float g = gacc[mf][nf][i], u = uacc[mf][nf][i];
          float h = g / (1.f + __expf(-g)) * u;   // silu(g)*u
          hbuf[base + nf * 16 + fr] = f2bf(h);
        }
      }
    }
}

// ---------------- GEMM2: wout[pos] = w * (h @ Wd^T) ----------------
// Round-6 proven config, FROZEN this round for attribution.
__launch_bounds__(256, 4)
__global__ void gemm2_kernel(const unsigned short* __restrict__ hbuf,
                             const unsigned short* __restrict__ wdb,
                             const int* __restrict__ cnt,
                             const float* __restrict__ wts, unsigned short* __restrict__ wout) {
  TileInfo ti;
  if (!tile_lookup(cnt, blockIdx.y, ti)) return;
  const int tid = threadIdx.x;
  const int e = ti.e, ts = ti.ts, segBase = ti.segBase, segN = ti.segN;
  const int ncol0 = blockIdx.x * BN;

  __shared__ unsigned short lds[2][2][BM][BK];   // 32 KiB

  const int r0 = tid >> 2, r1 = 64 + (tid >> 2);
  const int kq = (tid & 3) * 8;
  int ar0 = ts + r0; if (ar0 >= segN) ar0 = segN - 1;
  int ar1 = ts + r1; if (ar1 >= segN) ar1 = segN - 1;
  const unsigned short* ag0 = hbuf + (size_t)(segBase + ar0) * H_DIM + kq;
  const unsigned short* ag1 = hbuf + (size_t)(segBase + ar1) * H_DIM + kq;
  const unsigned short* wde = wdb + (size_t)e * DOUT_ * H_DIM;
  const unsigned short* bg0 = wde + (size_t)(ncol0 + r0) * H_DIM + kq;
  const unsigned short* bg1 = wde + (size_t)(ncol0 + r1) * H_DIM + kq;

#define STAGE2(b, k0) do { \
    gload16(ag0 + (k0), &lds[b][0][r0][kq]); \
    gload16(ag1 + (k0), &lds[b][0][r1][kq]); \
    gload16(bg0 + (k0), &lds[b][1][r0][kq]); \
    gload16(bg1 + (k0), &lds[b][1][r1][kq]); \
  } while (0)

  f32x4 acc[4][4] = {};
  const int lane = tid & 63, wid = tid >> 6;
  const int wm = (wid >> 1) * 64, wn = (wid & 1) * 64;
  const int fr = lane & 15, fq = lane >> 4;

  STAGE2(0, 0);
  __syncthreads();
  for (int kt = 0; kt < H_DIM / BK; ++kt) {
    const int cur = kt & 1;
    if (kt + 1 < H_DIM / BK) STAGE2(cur ^ 1, (kt + 1) * BK);
    bf16x8 af[4], bf[4];
#pragma unroll
    for (int mf = 0; mf < 4; ++mf) af[mf] = *(const bf16x8*)&lds[cur][0][wm + mf * 16 + fr][fq * 8];
#pragma unroll
    for (int nf = 0; nf < 4; ++nf) bf[nf] = *(const bf16x8*)&lds[cur][1][wn + nf * 16 + fr][fq * 8];
#pragma unroll
    for (int mf = 0; mf < 4; ++mf)
#pragma unroll
      for (int nf = 0; nf < 4; ++nf)
        acc[mf][nf] = __builtin_amdgcn_mfma_f32_16x16x32_bf16(af[mf], bf[nf], acc[mf][nf], 0, 0, 0);
    __syncthreads();
  }
#undef STAGE2

#pragma unroll
  for (int mf = 0; mf < 4; ++mf)
#pragma unroll
    for (int i = 0; i < 4; ++i) {
      int rloc = wm + mf * 16 + fq * 4 + i;
      int rseg = ts + rloc;
      if (rseg < segN) {
        float w = wts[segBase + rseg];
        unsigned short* obase = wout + (size_t)(segBase + rseg) * DOUT_ + ncol0 + wn;
#pragma unroll
        for (int nf = 0; nf < 4; ++nf)
          obase[nf * 16 + fr] = f2bf(acc[mf][nf][i] * w);
      }
    }
}

// ---------------- combine: out[t] = wout[inv[2t]] + wout[inv[2t+1]] (bf16 in) ----
__global__ void combine_kernel(const unsigned short* __restrict__ wout, const int* __restrict__ inv,
                               float* __restrict__ out) {
  const int total = T_TOK * (DOUT_ / 4);           // 4-elem chunks
  for (int i = blockIdx.x * blockDim.x + threadIdx.x; i < total;
       i += gridDim.x * blockDim.x) {
    int t = i >> 8;                                 // DOUT/4 = 256 chunks per token
    int c4 = (i & 255) << 2;
    int p0 = inv[2 * t], p1 = inv[2 * t + 1];
    ushort4 a = *(const ushort4*)(wout + ((size_t)p0 << 10) + c4);
    ushort4 b = *(const ushort4*)(wout + ((size_t)p1 << 10) + c4);
    float4 r;
    r.x = bf2f(a.x) + bf2f(b.x);
    r.y = bf2f(a.y) + bf2f(b.y);
    r.z = bf2f(a.z) + bf2f(b.z);
    r.w = bf2f(a.w) + bf2f(b.w);
    *(float4*)(out + ((size_t)t << 10) + c4) = r;
  }
}

// ---------------- launch ----------------
extern "C" void kernel_launch(void* const* d_in, const int* in_sizes, int n_in,
                              void* d_out, int out_size, void* d_ws, size_t ws_size,
                              hipStream_t stream) {
  const float* x   = (const float*)d_in[0];
  const int*   idx = (const int*)d_in[1];
  const float* tkw = (const float*)d_in[2];
  const float* wg  = (const float*)d_in[3];
  const float* wu  = (const float*)d_in[4];
  const float* wd  = (const float*)d_in[5];
  float* out = (float*)d_out;

  char* p = (char*)d_ws;
  // wout (bf16, 33.5 MB) aliases xb+wgb: dead after gemm1, rewritten by
  // convert at the start of every call -> deterministic.
  unsigned short* wout = (unsigned short*)p;
  unsigned short* xb   = (unsigned short*)p; p += (size_t)T_TOK * D_IN * 2;
  unsigned short* wgb  = (unsigned short*)p; p += (size_t)NEXP * H_DIM * D_IN * 2;
  unsigned short* wub  = (unsigned short*)p; p += (size_t)NEXP * H_DIM * D_IN * 2;
  unsigned short* wdb  = (unsigned short*)p; p += (size_t)NEXP * DOUT_ * H_DIM * 2;
  unsigned short* hbuf = (unsigned short*)p; p += (size_t)NPAIR * H_DIM * 2;
  int*   rows = (int*)p;   p += NPAIR * 4;
  float* wts  = (float*)p; p += NPAIR * 4;
  int*   inv  = (int*)p;   p += NPAIR * 4;
  int*   cnt  = (int*)p;   p += NEXP * 4;

  convert_kernel<<<2048, 256, 0, stream>>>(x, wg, wu, wd, xb, wgb, wub, wdb);
  dispatch_kernel<<<1, 1024, 0, stream>>>(idx, tkw, cnt, rows, wts, inv);
  gemm1_kernel<<<dim3(H_DIM / BN, MAX_TILES), 256, 0, stream>>>(xb, wgb, wub, cnt, rows, hbuf);
  gemm2_kernel<<<dim3(DOUT_ / BN, MAX_TILES), 256, 0, stream>>>(hbuf, wdb, cnt, wts, wout);
  combine_kernel<<<2048, 256, 0, stream>>>(wout, inv, out);
}